// Round 6
// baseline (557.549 us; speedup 1.0000x reference)
//
#include <hip/hip_runtime.h>

#define N_NODES 100000
#define N_EDGES 1600000
#define N_SCAN_BLOCKS ((N_NODES + 255) / 256)   // 391
#define SCAT_CHUNK 4096
#define SCAT_NCHUNK ((N_EDGES + SCAT_CHUNK - 1) / SCAT_CHUNK)  // 391

// ============ CSR construction (counting sort by dst, atomic-free scatter) ==

__global__ __launch_bounds__(256) void k_hist(const int* __restrict__ ei,
                                              int* __restrict__ cnt,
                                              int* __restrict__ rank)
{
    int e = blockIdx.x * 256 + threadIdx.x;
    if (e >= N_EDGES) return;
    rank[e] = atomicAdd(&cnt[ei[N_EDGES + e]], 1);
}

__global__ __launch_bounds__(256) void k_scan_block(const int* __restrict__ cnt,
                                                    int* __restrict__ row_start,
                                                    int* __restrict__ partial)
{
    __shared__ int s[256];
    int i = blockIdx.x * 256 + threadIdx.x;
    int v = (i < N_NODES) ? cnt[i] : 0;
    s[threadIdx.x] = v;
    __syncthreads();
    for (int off = 1; off < 256; off <<= 1) {
        int t = (threadIdx.x >= off) ? s[threadIdx.x - off] : 0;
        __syncthreads();
        s[threadIdx.x] += t;
        __syncthreads();
    }
    if (i < N_NODES) row_start[i] = s[threadIdx.x] - v;   // exclusive
    if (threadIdx.x == 255) partial[blockIdx.x] = s[255]; // block total
}

__global__ __launch_bounds__(512) void k_scan_top(int* __restrict__ partial)
{
    __shared__ int s[512];
    int v = (threadIdx.x < N_SCAN_BLOCKS) ? partial[threadIdx.x] : 0;
    s[threadIdx.x] = v;
    __syncthreads();
    for (int off = 1; off < 512; off <<= 1) {
        int t = (threadIdx.x >= off) ? s[threadIdx.x - off] : 0;
        __syncthreads();
        s[threadIdx.x] += t;
        __syncthreads();
    }
    if (threadIdx.x < N_SCAN_BLOCKS) partial[threadIdx.x] = s[threadIdx.x] - v;
}

__global__ __launch_bounds__(256) void k_scan_add(int* __restrict__ row_start,
                                                 const int* __restrict__ partial)
{
    int i = blockIdx.x * 256 + threadIdx.x;
    if (i < N_NODES) row_start[i] += partial[i >> 8];
    if (i == 0) row_start[N_NODES] = N_EDGES;
}

// XCD-partitioned scatter: block b -> slot=b&7 (round-robin ~XCD), writes only
// dsts in its 1/8 node range so each sorted_src cache line is owned by one XCD.
__global__ __launch_bounds__(256) void k_scatter_xcd(const int* __restrict__ ei,
                                                     const int* __restrict__ row_start,
                                                     const int* __restrict__ rank,
                                                     int* __restrict__ sorted_src)
{
    int slot = blockIdx.x & 7;
    int chunk = blockIdx.x >> 3;
    int lo = slot * (N_NODES / 8), hi = lo + (N_NODES / 8);
    int base = chunk * SCAT_CHUNK;
    for (int i = threadIdx.x; i < SCAT_CHUNK; i += 256) {
        int e = base + i;
        if (e >= N_EDGES) break;
        int dst = ei[N_EDGES + e];
        if (dst >= lo && dst < hi)
            sorted_src[row_start[dst] + rank[e]] = ei[e];
    }
}

// ============ fused agg1 + node transform: one wave per node ============
// Gather (lane=dim) -> mean; layer1 (lane=j) via per-wave LDS broadcast of
// mean/xrow; layer2 (lanes 0-31 -> t2, 32-63 -> t3). Weight reads are
// lane-contiguous b32 (2-way bank alias only = free). h never hits memory.
__global__ __launch_bounds__(256, 3) void k_fused1(
    const int* __restrict__ row_start, const int* __restrict__ sorted_src,
    const float* __restrict__ x,
    const float* __restrict__ W1l, const float* __restrict__ b1l,
    const float* __restrict__ W1r, const float* __restrict__ W2l,
    const float* __restrict__ W2r,
    float* __restrict__ t2, float* __restrict__ t3)
{
    __shared__ float sW1l[64 * 64];
    __shared__ float sW1r[64 * 64];
    __shared__ float sW2l[64 * 32];
    __shared__ float sW2r[64 * 32];
    __shared__ float sB[4][128];   // per-wave: [0,64)=mean then h; [64,128)=x row
    {
        float4* d1 = (float4*)sW1l; const float4* g1 = (const float4*)W1l;
        float4* d2 = (float4*)sW1r; const float4* g2 = (const float4*)W1r;
        for (int i = threadIdx.x; i < 1024; i += 256) { d1[i] = g1[i]; d2[i] = g2[i]; }
        float4* d3 = (float4*)sW2l; const float4* g3 = (const float4*)W2l;
        float4* d4 = (float4*)sW2r; const float4* g4 = (const float4*)W2r;
        for (int i = threadIdx.x; i < 512; i += 256) { d3[i] = g3[i]; d4[i] = g4[i]; }
    }
    __syncthreads();

    int w = threadIdx.x >> 6, lane = threadIdx.x & 63;
    int n = blockIdx.x * 4 + w;
    if (n >= N_NODES) return;

    int beg = row_start[n], end = row_start[n + 1];
    float a0 = 0.0f, a1 = 0.0f;
    int idx = beg;
    for (; idx + 2 <= end; idx += 2) {
        int s0 = sorted_src[idx];
        int s1 = sorted_src[idx + 1];
        a0 += x[(size_t)s0 * 64 + lane];
        a1 += x[(size_t)s1 * 64 + lane];
    }
    if (idx < end) a0 += x[(size_t)sorted_src[idx] * 64 + lane];
    float inv = 1.0f / fmaxf((float)(end - beg), 1.0f);
    sB[w][lane]      = (a0 + a1) * inv;          // mean (lane = dim)
    sB[w][64 + lane] = x[(size_t)n * 64 + lane]; // own feature row
    // wave-synchronous LDS: all 64 lanes issue writes before any dependent read
    // in program order; compiler inserts the lgkmcnt.

    // ---- layer 1: lane j computes h[j] ----
    float h = b1l[lane];
    const float4* mv = (const float4*)&sB[w][0];
    const float4* xv = (const float4*)&sB[w][64];
    for (int kk = 0; kk < 16; kk++) {
        float4 m4 = mv[kk];      // uniform-address broadcast
        float4 x4 = xv[kk];
        float ms[4] = {m4.x, m4.y, m4.z, m4.w};
        float xs[4] = {x4.x, x4.y, x4.z, x4.w};
#pragma unroll
        for (int u = 0; u < 4; u++) {
            int k = kk * 4 + u;
            h += ms[u] * sW1l[k * 64 + lane] + xs[u] * sW1r[k * 64 + lane];
        }
    }
    h = fmaxf(h, 0.0f);
    sB[w][lane] = h;             // overwrite mean slot (all mean reads precede)

    // ---- layer 2: lanes 0-31 -> t2[o], lanes 32-63 -> t3[o] ----
    int o = lane & 31;
    const float* W = (lane < 32) ? sW2l : sW2r;
    float acc = 0.0f;
    const float4* hv = (const float4*)&sB[w][0];
    for (int kk = 0; kk < 16; kk++) {
        float4 h4 = hv[kk];      // uniform-address broadcast
        float hs[4] = {h4.x, h4.y, h4.z, h4.w};
#pragma unroll
        for (int u = 0; u < 4; u++)
            acc += hs[u] * W[(kk * 4 + u) * 32 + o];
    }
    float* dstp = (lane < 32) ? (t2 + (size_t)n * 32 + o)
                              : (t3 + (size_t)n * 32 + o);
    *dstp = acc;
}

// ============ fused agg2 + output: out = (sum t2[src])/deg + t3 + b2l ======
__global__ __launch_bounds__(256) void k_agg2out(
    const int* __restrict__ row_start, const int* __restrict__ sorted_src,
    const float* __restrict__ t2, const float* __restrict__ t3,
    const float* __restrict__ b2l, float* __restrict__ out)
{
    int node = blockIdx.x * 8 + (threadIdx.x >> 5);
    if (node >= N_NODES) return;
    int d = threadIdx.x & 31;
    int beg = row_start[node], end = row_start[node + 1];
    float a0 = 0.0f, a1 = 0.0f;
    int idx = beg;
    for (; idx + 2 <= end; idx += 2) {
        int s0 = sorted_src[idx];
        int s1 = sorted_src[idx + 1];
        a0 += t2[(size_t)s0 * 32 + d];
        a1 += t2[(size_t)s1 * 32 + d];
    }
    if (idx < end) a0 += t2[(size_t)sorted_src[idx] * 32 + d];
    float deg = (float)(end - beg);
    float inv = 1.0f / fmaxf(deg, 1.0f);
    out[(size_t)node * 32 + d] = (a0 + a1) * inv + t3[(size_t)node * 32 + d] + b2l[d];
}

extern "C" void kernel_launch(void* const* d_in, const int* in_sizes, int n_in,
                              void* d_out, int out_size, void* d_ws, size_t ws_size,
                              hipStream_t stream) {
    const float* x   = (const float*)d_in[0];
    const int*   ei  = (const int*)d_in[1];
    const float* W1l = (const float*)d_in[2];
    const float* b1l = (const float*)d_in[3];
    const float* W1r = (const float*)d_in[4];
    const float* W2l = (const float*)d_in[5];
    const float* b2l = (const float*)d_in[6];
    const float* W2r = (const float*)d_in[7];
    float* out = (float*)d_out;

    const size_t N = N_NODES, E = N_EDGES;
    int* wsi = (int*)d_ws;
    int* cnt        = wsi;                     // N
    int* row_start  = wsi + N;                 // N+1
    int* partial    = wsi + 2 * N + 1;         // 512
    int* rank       = wsi + 2 * N + 513;       // E
    int* sorted_src = wsi + 2 * N + 513 + E;   // E
    float* wsf = (float*)(wsi + 2 * N + 513 + 2 * E);
    float* t2   = wsf;                         // 32N
    float* t3   = wsf + 32 * N;                // 32N
    // total: (2N+513+2E)*4 + 64N*4 ~= 39 MB

    hipMemsetAsync(cnt, 0, N * sizeof(int), stream);
    k_hist      <<<(E + 255) / 256, 256, 0, stream>>>(ei, cnt, rank);
    k_scan_block<<<N_SCAN_BLOCKS, 256, 0, stream>>>(cnt, row_start, partial);
    k_scan_top  <<<1, 512, 0, stream>>>(partial);
    k_scan_add  <<<N_SCAN_BLOCKS, 256, 0, stream>>>(row_start, partial);
    k_scatter_xcd<<<SCAT_NCHUNK * 8, 256, 0, stream>>>(ei, row_start, rank, sorted_src);

    k_fused1 <<<(int)((N + 3) / 4), 256, 0, stream>>>(row_start, sorted_src, x,
                                                W1l, b1l, W1r, W2l, W2r, t2, t3);
    k_agg2out<<<(int)(N / 8), 256, 0, stream>>>(row_start, sorted_src, t2, t3, b2l, out);
}

// Round 7
// 424.424 us; speedup vs baseline: 1.3137x; 1.3137x over previous
//
#include <hip/hip_runtime.h>

#define N_NODES 100000
#define N_EDGES 1600000
#define N_SCAN_BLOCKS ((N_NODES + 255) / 256)   // 391
#define BK_SHIFT 10
#define NBUCK ((N_NODES + 1023) >> 10)          // 98 buckets of 1024 nodes
#define EB_PER_BLOCK 2048
#define NBUCK_BLOCKS ((N_EDGES + EB_PER_BLOCK - 1) / EB_PER_BLOCK)  // 782

// ============ CSR construction ============

__global__ __launch_bounds__(256) void k_hist(const int* __restrict__ ei,
                                              int* __restrict__ cnt,
                                              int* __restrict__ rank)
{
    int e = blockIdx.x * 256 + threadIdx.x;
    if (e >= N_EDGES) return;
    rank[e] = atomicAdd(&cnt[ei[N_EDGES + e]], 1);
}

__global__ __launch_bounds__(256) void k_scan_block(const int* __restrict__ cnt,
                                                    int* __restrict__ row_start,
                                                    int* __restrict__ partial)
{
    __shared__ int s[256];
    int i = blockIdx.x * 256 + threadIdx.x;
    int v = (i < N_NODES) ? cnt[i] : 0;
    s[threadIdx.x] = v;
    __syncthreads();
    for (int off = 1; off < 256; off <<= 1) {
        int t = (threadIdx.x >= off) ? s[threadIdx.x - off] : 0;
        __syncthreads();
        s[threadIdx.x] += t;
        __syncthreads();
    }
    if (i < N_NODES) row_start[i] = s[threadIdx.x] - v;   // exclusive
    if (threadIdx.x == 255) partial[blockIdx.x] = s[255]; // block total
}

__global__ __launch_bounds__(512) void k_scan_top(int* __restrict__ partial)
{
    __shared__ int s[512];
    int v = (threadIdx.x < N_SCAN_BLOCKS) ? partial[threadIdx.x] : 0;
    s[threadIdx.x] = v;
    __syncthreads();
    for (int off = 1; off < 512; off <<= 1) {
        int t = (threadIdx.x >= off) ? s[threadIdx.x - off] : 0;
        __syncthreads();
        s[threadIdx.x] += t;
        __syncthreads();
    }
    if (threadIdx.x < N_SCAN_BLOCKS) partial[threadIdx.x] = s[threadIdx.x] - v;
}

__global__ __launch_bounds__(256) void k_scan_add(int* __restrict__ row_start,
                                                 const int* __restrict__ partial)
{
    int i = blockIdx.x * 256 + threadIdx.x;
    if (i < N_NODES) row_start[i] += partial[i >> 8];
    if (i == 0) row_start[N_NODES] = N_EDGES;
}

// bucket b's cursor starts at the CSR offset of its first node
__global__ __launch_bounds__(128) void k_bcur_init(const int* __restrict__ row_start,
                                                   int* __restrict__ bcur)
{
    int b = threadIdx.x;
    if (b < NBUCK) bcur[b] = row_start[b << BK_SHIFT];
}

// Pass A: append (src, final_pos) into per-bucket regions (LDS-ranked).
__global__ __launch_bounds__(256) void k_bucketA(const int* __restrict__ ei,
                                                 const int* __restrict__ rank,
                                                 const int* __restrict__ row_start,
                                                 int* __restrict__ bcur,
                                                 int* __restrict__ bsrc,
                                                 int* __restrict__ bpos)
{
    __shared__ int lh[NBUCK];
    __shared__ int lbase[NBUCK];
    for (int i = threadIdx.x; i < NBUCK; i += 256) lh[i] = 0;
    __syncthreads();

    int base = blockIdx.x * EB_PER_BLOCK;
    int myb[8], myr[8], mysrc[8], mypos[8];
#pragma unroll
    for (int t = 0; t < 8; t++) {
        int e = base + t * 256 + threadIdx.x;
        myb[t] = -1;
        if (e < N_EDGES) {
            int dst = ei[N_EDGES + e];
            int b = dst >> BK_SHIFT;
            myb[t] = b;
            myr[t] = atomicAdd(&lh[b], 1);
            mysrc[t] = ei[e];
            mypos[t] = row_start[dst] + rank[e];
        }
    }
    __syncthreads();
    for (int i = threadIdx.x; i < NBUCK; i += 256)
        lbase[i] = lh[i] ? atomicAdd(&bcur[i], lh[i]) : 0;
    __syncthreads();
#pragma unroll
    for (int t = 0; t < 8; t++) {
        if (myb[t] >= 0) {
            int slot = lbase[myb[t]] + myr[t];
            bsrc[slot] = mysrc[t];
            bpos[slot] = mypos[t];
        }
    }
}

// Pass B: consecutive i share a bucket -> stores hit an L2-resident 64KB window.
__global__ __launch_bounds__(256) void k_bucketB(const int* __restrict__ bsrc,
                                                 const int* __restrict__ bpos,
                                                 int* __restrict__ sorted_src)
{
    int i = blockIdx.x * 256 + threadIdx.x;
    if (i >= N_EDGES) return;
    sorted_src[bpos[i]] = bsrc[i];
}

// ============ agg1: wave per node, lane = dim ============

__global__ __launch_bounds__(256) void k_agg1(const int* __restrict__ row_start,
                                              const int* __restrict__ sorted_src,
                                              const float* __restrict__ x,
                                              float* __restrict__ agg1)
{
    int node = blockIdx.x * 4 + (threadIdx.x >> 6);
    if (node >= N_NODES) return;
    int d = threadIdx.x & 63;
    int beg = row_start[node], end = row_start[node + 1];
    float a0 = 0.0f, a1 = 0.0f;
    int idx = beg;
    for (; idx + 2 <= end; idx += 2) {
        int s0 = sorted_src[idx];
        int s1 = sorted_src[idx + 1];
        a0 += x[(size_t)s0 * 64 + d];
        a1 += x[(size_t)s1 * 64 + d];
    }
    if (idx < end) a0 += x[(size_t)sorted_src[idx] * 64 + d];
    agg1[(size_t)node * 64 + d] = a0 + a1;
}

// ============ node transform: 4 threads/node, conflict-free LDS ============
// Thread jg owns interleaved float4-chunks c = 4q+jg of j-space (j = 4c..4c+3):
// per ds_read_b128 the 4 distinct jg addresses hit 16 disjoint banks.
// sW2 rows padded to 36 floats (144 B) -> layer-2 2-way alias only (free).
#define W2S 36
__global__ __launch_bounds__(256, 3) void k_node(
    const float* __restrict__ x, const float* __restrict__ agg1,
    const int* __restrict__ row_start,
    const float* __restrict__ W1l, const float* __restrict__ b1l,
    const float* __restrict__ W1r, const float* __restrict__ W2l,
    const float* __restrict__ W2r,
    float* __restrict__ t2, float* __restrict__ t3)
{
    __shared__ float sW1l[64 * 64];
    __shared__ float sW1r[64 * 64];
    __shared__ float sW2l[64 * W2S];
    __shared__ float sW2r[64 * W2S];
    {
        float4* d1 = (float4*)sW1l; const float4* g1 = (const float4*)W1l;
        float4* d2 = (float4*)sW1r; const float4* g2 = (const float4*)W1r;
        for (int i = threadIdx.x; i < 1024; i += 256) { d1[i] = g1[i]; d2[i] = g2[i]; }
        const float4* g3 = (const float4*)W2l;
        const float4* g4 = (const float4*)W2r;
        for (int i = threadIdx.x; i < 512; i += 256) {
            int j = i >> 3, q = i & 7;
            *(float4*)(sW2l + j * W2S + q * 4) = g3[i];
            *(float4*)(sW2r + j * W2S + q * 4) = g4[i];
        }
    }
    __syncthreads();

    int t = blockIdx.x * 256 + threadIdx.x;
    int n = t >> 2;
    if (n >= N_NODES) return;
    int jg = t & 3;          // owns j = 16q + 4jg + e  (q,e in 0..3)
    float degf = (float)(row_start[n + 1] - row_start[n]);
    float inv = 1.0f / fmaxf(degf, 1.0f);

    float acc[16];
    {
        const float4* bv = (const float4*)b1l;
#pragma unroll
        for (int q = 0; q < 4; q++) {
            float4 b4 = bv[4 * q + jg];
            acc[4*q+0] = b4.x; acc[4*q+1] = b4.y;
            acc[4*q+2] = b4.z; acc[4*q+3] = b4.w;
        }
    }

    const float4* av = (const float4*)(agg1 + (size_t)n * 64);
    const float4* xv = (const float4*)(x + (size_t)n * 64);
    for (int kk = 0; kk < 16; kk++) {
        float4 a4 = av[kk];
        float4 x4 = xv[kk];
        float as[4] = {a4.x * inv, a4.y * inv, a4.z * inv, a4.w * inv};
        float xs[4] = {x4.x, x4.y, x4.z, x4.w};
#pragma unroll
        for (int u = 0; u < 4; u++) {
            int k = kk * 4 + u;
            const float4* wlr = (const float4*)(sW1l + k * 64);
            const float4* wrr = (const float4*)(sW1r + k * 64);
#pragma unroll
            for (int q = 0; q < 4; q++) {
                float4 l4 = wlr[4 * q + jg], r4 = wrr[4 * q + jg];
                acc[4*q+0] += as[u] * l4.x + xs[u] * r4.x;
                acc[4*q+1] += as[u] * l4.y + xs[u] * r4.y;
                acc[4*q+2] += as[u] * l4.z + xs[u] * r4.z;
                acc[4*q+3] += as[u] * l4.w + xs[u] * r4.w;
            }
        }
    }

    // layer 2: k-partial over this thread's 16 j's, full 32-wide output
    float o2[32], o3[32];
#pragma unroll
    for (int o = 0; o < 32; o++) { o2[o] = 0.0f; o3[o] = 0.0f; }
#pragma unroll
    for (int q = 0; q < 4; q++) {
#pragma unroll
        for (int e = 0; e < 4; e++) {
            float hj = fmaxf(acc[4*q+e], 0.0f);
            int j = 16 * q + 4 * jg + e;
            const float4* w2 = (const float4*)(sW2l + j * W2S);
            const float4* w3 = (const float4*)(sW2r + j * W2S);
#pragma unroll
            for (int qq = 0; qq < 8; qq++) {
                float4 a = w2[qq], b = w3[qq];
                o2[4*qq+0] += hj * a.x;  o3[4*qq+0] += hj * b.x;
                o2[4*qq+1] += hj * a.y;  o3[4*qq+1] += hj * b.y;
                o2[4*qq+2] += hj * a.z;  o3[4*qq+2] += hj * b.z;
                o2[4*qq+3] += hj * a.w;  o3[4*qq+3] += hj * b.w;
            }
        }
    }
    // quad reduce across the 4 lanes of this node
#pragma unroll
    for (int o = 0; o < 32; o++) {
        o2[o] += __shfl_xor(o2[o], 1);
        o2[o] += __shfl_xor(o2[o], 2);
        o3[o] += __shfl_xor(o3[o], 1);
        o3[o] += __shfl_xor(o3[o], 2);
    }
    // lane stores its 8-wide slice (compile-time indices -> no scratch)
    float4* t2v = (float4*)(t2 + (size_t)n * 32 + jg * 8);
    float4* t3v = (float4*)(t3 + (size_t)n * 32 + jg * 8);
    if (jg == 0) {
        t2v[0] = make_float4(o2[0], o2[1], o2[2], o2[3]);
        t2v[1] = make_float4(o2[4], o2[5], o2[6], o2[7]);
        t3v[0] = make_float4(o3[0], o3[1], o3[2], o3[3]);
        t3v[1] = make_float4(o3[4], o3[5], o3[6], o3[7]);
    } else if (jg == 1) {
        t2v[0] = make_float4(o2[8], o2[9], o2[10], o2[11]);
        t2v[1] = make_float4(o2[12], o2[13], o2[14], o2[15]);
        t3v[0] = make_float4(o3[8], o3[9], o3[10], o3[11]);
        t3v[1] = make_float4(o3[12], o3[13], o3[14], o3[15]);
    } else if (jg == 2) {
        t2v[0] = make_float4(o2[16], o2[17], o2[18], o2[19]);
        t2v[1] = make_float4(o2[20], o2[21], o2[22], o2[23]);
        t3v[0] = make_float4(o3[16], o3[17], o3[18], o3[19]);
        t3v[1] = make_float4(o3[20], o3[21], o3[22], o3[23]);
    } else {
        t2v[0] = make_float4(o2[24], o2[25], o2[26], o2[27]);
        t2v[1] = make_float4(o2[28], o2[29], o2[30], o2[31]);
        t3v[0] = make_float4(o3[24], o3[25], o3[26], o3[27]);
        t3v[1] = make_float4(o3[28], o3[29], o3[30], o3[31]);
    }
}

// ============ fused agg2 + output: out = (sum t2[src])/deg + t3 + b2l ======
__global__ __launch_bounds__(256) void k_agg2out(
    const int* __restrict__ row_start, const int* __restrict__ sorted_src,
    const float* __restrict__ t2, const float* __restrict__ t3,
    const float* __restrict__ b2l, float* __restrict__ out)
{
    int node = blockIdx.x * 8 + (threadIdx.x >> 5);
    if (node >= N_NODES) return;
    int d = threadIdx.x & 31;
    int beg = row_start[node], end = row_start[node + 1];
    float a0 = 0.0f, a1 = 0.0f;
    int idx = beg;
    for (; idx + 2 <= end; idx += 2) {
        int s0 = sorted_src[idx];
        int s1 = sorted_src[idx + 1];
        a0 += t2[(size_t)s0 * 32 + d];
        a1 += t2[(size_t)s1 * 32 + d];
    }
    if (idx < end) a0 += t2[(size_t)sorted_src[idx] * 32 + d];
    float deg = (float)(end - beg);
    float inv = 1.0f / fmaxf(deg, 1.0f);
    out[(size_t)node * 32 + d] = (a0 + a1) * inv + t3[(size_t)node * 32 + d] + b2l[d];
}

extern "C" void kernel_launch(void* const* d_in, const int* in_sizes, int n_in,
                              void* d_out, int out_size, void* d_ws, size_t ws_size,
                              hipStream_t stream) {
    const float* x   = (const float*)d_in[0];
    const int*   ei  = (const int*)d_in[1];
    const float* W1l = (const float*)d_in[2];
    const float* b1l = (const float*)d_in[3];
    const float* W1r = (const float*)d_in[4];
    const float* W2l = (const float*)d_in[5];
    const float* b2l = (const float*)d_in[6];
    const float* W2r = (const float*)d_in[7];
    float* out = (float*)d_out;

    const size_t N = N_NODES, E = N_EDGES;
    int* wsi = (int*)d_ws;
    int* cnt        = wsi;                         // N
    int* row_start  = wsi + N;                     // N+1
    int* partial    = wsi + 2 * N + 1;             // 512
    int* rank       = wsi + 2 * N + 513;           // E
    int* sorted_src = wsi + 2 * N + 513 + E;       // E
    int* bsrc       = wsi + 2 * N + 513 + 2 * E;   // E
    int* bpos       = wsi + 2 * N + 513 + 3 * E;   // E
    int* bcur       = wsi + 2 * N + 513 + 4 * E;   // 128
    float* wsf = (float*)(bcur + 128);
    float* agg1 = wsf;                             // 64N
    float* t2   = wsf + 64 * N;                    // 32N
    float* t3   = wsf + 96 * N;                    // 32N
    // total ~= (2N+513+4E+128)*4 + 128N*4 ~= 77 MB

    hipMemsetAsync(cnt, 0, N * sizeof(int), stream);
    k_hist      <<<(E + 255) / 256, 256, 0, stream>>>(ei, cnt, rank);
    k_scan_block<<<N_SCAN_BLOCKS, 256, 0, stream>>>(cnt, row_start, partial);
    k_scan_top  <<<1, 512, 0, stream>>>(partial);
    k_scan_add  <<<N_SCAN_BLOCKS, 256, 0, stream>>>(row_start, partial);
    k_bcur_init <<<1, 128, 0, stream>>>(row_start, bcur);
    k_bucketA   <<<NBUCK_BLOCKS, 256, 0, stream>>>(ei, rank, row_start, bcur, bsrc, bpos);
    k_bucketB   <<<(E + 255) / 256, 256, 0, stream>>>(bsrc, bpos, sorted_src);

    k_agg1   <<<(int)(N / 4), 256, 0, stream>>>(row_start, sorted_src, x, agg1);
    k_node   <<<(int)((N * 4 + 255) / 256), 256, 0, stream>>>(x, agg1, row_start,
                                                W1l, b1l, W1r, W2l, W2r, t2, t3);
    k_agg2out<<<(int)(N / 8), 256, 0, stream>>>(row_start, sorted_src, t2, t3, b2l, out);
}